// Round 15
// baseline (4303.962 us; speedup 1.0000x reference)
//
#include <hip/hip_runtime.h>

#define T_N 4096
#define B_N 64
#define I_N 128
#define H_N 128
#define BH  (B_N * H_N)

typedef _Float16 h2   __attribute__((ext_vector_type(2)));
typedef _Float16 h8   __attribute__((ext_vector_type(8)));
typedef __fp16   fp16x2 __attribute__((ext_vector_type(2)));

// ---------------------------------------------------------------------------
// Phase 1: xp = x @ W_ih^T + b_ih -> into out (in-place with phase 2).
// Unchanged from R2-R14 (~70 us).
// ---------------------------------------------------------------------------
__global__ __launch_bounds__(256) void xproj_kernel(
    const float* __restrict__ x, const float* __restrict__ Wih,
    const float* __restrict__ bih, float* __restrict__ xp)
{
    __shared__ float wt[I_N][H_N];   // wt[k][j] = Wih[j][k], 64 KB
    const int tid = threadIdx.x;

    {
        const float4* w4 = (const float4*)Wih;
        #pragma unroll
        for (int it = 0; it < 16; ++it) {
            int i = tid * 16 + it;          // 0..4095 float4s
            float4 v = w4[i];
            int r = i >> 5;                 // W row j
            int k = (i & 31) << 2;          // k base
            wt[k + 0][r] = v.x;
            wt[k + 1][r] = v.y;
            wt[k + 2][r] = v.z;
            wt[k + 3][r] = v.w;
        }
    }
    __syncthreads();

    const int  tx   = tid & 15;
    const int  ty   = tid >> 4;
    const long row0 = (long)blockIdx.x * 128;
    const float* xbase = x + (row0 + ty * 8) * I_N;

    float acc[8][8];
    #pragma unroll
    for (int r = 0; r < 8; ++r)
        #pragma unroll
        for (int c = 0; c < 8; ++c) acc[r][c] = 0.0f;

    #pragma unroll 2
    for (int k4 = 0; k4 < I_N / 4; ++k4) {
        float4 xv[8];
        #pragma unroll
        for (int r = 0; r < 8; ++r)
            xv[r] = *(const float4*)(xbase + r * I_N + k4 * 4);

        #pragma unroll
        for (int kk = 0; kk < 4; ++kk) {
            int k = k4 * 4 + kk;
            float4 w0 = *(const float4*)&wt[k][tx * 4];
            float4 w1 = *(const float4*)&wt[k][64 + tx * 4];
            #pragma unroll
            for (int r = 0; r < 8; ++r) {
                float xk = (kk == 0) ? xv[r].x : (kk == 1) ? xv[r].y
                         : (kk == 2) ? xv[r].z : xv[r].w;
                acc[r][0] = fmaf(xk, w0.x, acc[r][0]);
                acc[r][1] = fmaf(xk, w0.y, acc[r][1]);
                acc[r][2] = fmaf(xk, w0.z, acc[r][2]);
                acc[r][3] = fmaf(xk, w0.w, acc[r][3]);
                acc[r][4] = fmaf(xk, w1.x, acc[r][4]);
                acc[r][5] = fmaf(xk, w1.y, acc[r][5]);
                acc[r][6] = fmaf(xk, w1.z, acc[r][6]);
                acc[r][7] = fmaf(xk, w1.w, acc[r][7]);
            }
        }
    }

    float4 b0 = *(const float4*)(bih + tx * 4);
    float4 b1 = *(const float4*)(bih + 64 + tx * 4);
    #pragma unroll
    for (int r = 0; r < 8; ++r) {
        long row = row0 + ty * 8 + r;
        float4 o0, o1;
        o0.x = acc[r][0] + b0.x;  o0.y = acc[r][1] + b0.y;
        o0.z = acc[r][2] + b0.z;  o0.w = acc[r][3] + b0.w;
        o1.x = acc[r][4] + b1.x;  o1.y = acc[r][5] + b1.y;
        o1.z = acc[r][6] + b1.z;  o1.w = acc[r][7] + b1.w;
        *(float4*)(xp + row * H_N + tx * 4)      = o0;
        *(float4*)(xp + row * H_N + 64 + tx * 4) = o1;
    }
}

// ---------------------------------------------------------------------------
// Phase 2 (R15): R9 structure + fp16 state + v_dot2_f32_f16.
// 64 blocks x 512 threads (8 waves, 2/SIMD -- measured occupancy optimum).
// Thread (p = lane&3 -> k-chunk [32p,32p+32), j = (lane>>2)&15 + 16*wv).
// h kept fp16 in LDS hbuf[2][4][36] (chunk-padded; reads are 4-distinct-
// address BROADCASTS -> ~free, the R12/R14 lesson). Per thread: 4
// ds_read_b128 (8 halfs each), 16 fdot2 (2 MACs/inst, f32 accum; halves
// the dominant MAC-issue term vs R9's 32 v_fma_f32), 2-level tree, DPP
// xor1+xor2 reduce, masked tanh + fp16 ds_write + f32 out store on p==0.
// W fragment pre-converted to fp16 (h2 pairs) at kernel entry.
// ---------------------------------------------------------------------------
__device__ __forceinline__ float tanh_pade(float x) {
    float u = x * x;
    float n = fmaf(u, u + 105.0f, 945.0f);              // u^2 + 105u + 945
    float d = fmaf(u, fmaf(15.0f, u, 420.0f), 945.0f);  // 15u^2 + 420u + 945
    float t = x * n * __builtin_amdgcn_rcpf(d);
    return fminf(1.0f, fmaxf(-1.0f, t));                // v_med3_f32
}

#define DPP_XOR1 0xB1   // quad_perm [1,0,3,2]
#define DPP_XOR2 0x4E   // quad_perm [2,3,0,1]

__device__ __forceinline__ float dpp_add(float v, const int ctrl) {
    int s = __float_as_int(v);
    int r;
    switch (ctrl) {  // ctrl must be a literal
        case DPP_XOR1: r = __builtin_amdgcn_update_dpp(0, s, DPP_XOR1, 0xF, 0xF, true); break;
        default:       r = __builtin_amdgcn_update_dpp(0, s, DPP_XOR2, 0xF, 0xF, true); break;
    }
    return v + __int_as_float(r);
}

#if __has_builtin(__builtin_amdgcn_fdot2)
__device__ __forceinline__ float dot2acc(h2 a, h2 b, float c) {
    return __builtin_amdgcn_fdot2(a, b, c, false);
}
#else
__device__ __forceinline__ float dot2acc(h2 a, h2 b, float c) {
    return fmaf((float)a[0], (float)b[0], fmaf((float)a[1], (float)b[1], c));
}
#endif

__global__ __launch_bounds__(512, 1) void scan_kernel(
    const float* __restrict__ Whh, const float* __restrict__ bhh,
    const float* __restrict__ h0, float* __restrict__ out)
{
    const int tid  = threadIdx.x;
    const int b    = blockIdx.x;
    const int lane = tid & 63;
    const int wv   = tid >> 6;                 // 0..7
    const int p    = lane & 3;                 // k-chunk [32p, 32p+32)
    const int j    = ((lane >> 2) & 15) + 16 * wv;  // output row 0..127
    __shared__ __align__(16) _Float16 hbuf[2][4][36];  // [buf][chunk][32+4 pad]

    // W fragment fp16: w2[c] = (W[j][32p+2c], W[j][32p+2c+1]), 16 pairs.
    h2 w2[16];
    {
        const float* wp = Whh + (size_t)j * H_N + 32 * p;
        #pragma unroll
        for (int c = 0; c < 16; ++c) {
            h2 t;
            t[0] = (_Float16)wp[2 * c];
            t[1] = (_Float16)wp[2 * c + 1];
            w2[c] = t;
        }
    }

    const float bh = bhh[j];

    if (tid < H_N) hbuf[0][tid >> 5][tid & 31] = (_Float16)h0[b * H_N + tid];

    const float* xq = out + b * H_N + j;   // xp (t,b,j) at xq + t*BH
    float*       oq = out + b * H_N + j;

    float xv[4];
    #pragma unroll
    for (int d = 0; d < 4; ++d)
        xv[d] = xq[(size_t)d * BH];

    __syncthreads();

#define RNN_STEP(T0, D, CUR) do {                                             \
        const h8* hb = (const h8*)&hbuf[CUR][p][0];                           \
        h8 H0 = hb[0], H1 = hb[1], H2 = hb[2], H3 = hb[3];                    \
        h2 hp[16];                                                            \
        _Pragma("unroll")                                                     \
        for (int m = 0; m < 4; ++m) {                                         \
            hp[m][0]      = H0[2 * m]; hp[m][1]      = H0[2 * m + 1];         \
            hp[4 + m][0]  = H1[2 * m]; hp[4 + m][1]  = H1[2 * m + 1];         \
            hp[8 + m][0]  = H2[2 * m]; hp[8 + m][1]  = H2[2 * m + 1];         \
            hp[12 + m][0] = H3[2 * m]; hp[12 + m][1] = H3[2 * m + 1];         \
        }                                                                     \
        float a0 = 0.f, a1 = 0.f, a2 = 0.f, a3 = 0.f;                         \
        _Pragma("unroll")                                                     \
        for (int c = 0; c < 4; ++c) {                                         \
            a0 = dot2acc(w2[c],      hp[c],      a0);                         \
            a1 = dot2acc(w2[4 + c],  hp[4 + c],  a1);                         \
            a2 = dot2acc(w2[8 + c],  hp[8 + c],  a2);                         \
            a3 = dot2acc(w2[12 + c], hp[12 + c], a3);                         \
        }                                                                     \
        float s = (a0 + a1) + (a2 + a3);                                      \
        s = dpp_add(s, DPP_XOR1);                                             \
        s = dpp_add(s, DPP_XOR2);                                             \
        float hj;                                                             \
        if (p == 0) {                                                         \
            hj = tanh_pade(s + xv[D] + bh);                                   \
            hbuf[(CUR) ^ 1][j >> 5][j & 31] = (_Float16)hj;                   \
        }                                                                     \
        if ((T0) + 4 < T_N)                                                   \
            xv[D] = xq[(size_t)((T0) + 4) * BH];                              \
        asm volatile("s_waitcnt lgkmcnt(0)" ::: "memory");                    \
        __builtin_amdgcn_s_barrier();                                         \
        if (p == 0) {                                                         \
            oq[(size_t)(T0) * BH] = hj;                                       \
            if ((T0) == T_N - 1) oq[(size_t)T_N * BH] = hj;                   \
        }                                                                     \
        asm volatile("" ::: "memory");                                        \
    } while (0)

    for (int t = 0; t < T_N; t += 4) {
        RNN_STEP(t + 0, 0, 0);
        RNN_STEP(t + 1, 1, 1);
        RNN_STEP(t + 2, 2, 0);
        RNN_STEP(t + 3, 3, 1);
    }
#undef RNN_STEP
}

extern "C" void kernel_launch(void* const* d_in, const int* in_sizes, int n_in,
                              void* d_out, int out_size, void* d_ws, size_t ws_size,
                              hipStream_t stream) {
    const float* x   = (const float*)d_in[0];
    const float* h0  = (const float*)d_in[1];
    const float* Wih = (const float*)d_in[2];
    const float* Whh = (const float*)d_in[3];
    const float* bih = (const float*)d_in[4];
    const float* bhh = (const float*)d_in[5];
    float* out = (float*)d_out;

    xproj_kernel<<<dim3((T_N * B_N) / 128), 256, 0, stream>>>(x, Wih, bih, out);
    scan_kernel<<<dim3(B_N), 512, 0, stream>>>(Whh, bhh, h0, out);
}

// Round 16
// 1488.912 us; speedup vs baseline: 2.8907x; 2.8907x over previous
//
#include <hip/hip_runtime.h>

#define T_N 4096
#define B_N 64
#define I_N 128
#define H_N 128
#define BH  (B_N * H_N)

// ---------------------------------------------------------------------------
// Phase 1: xp = x @ W_ih^T + b_ih -> into out (in-place with phase 2).
// Unchanged from R2-R15 (~70 us).
// ---------------------------------------------------------------------------
__global__ __launch_bounds__(256) void xproj_kernel(
    const float* __restrict__ x, const float* __restrict__ Wih,
    const float* __restrict__ bih, float* __restrict__ xp)
{
    __shared__ float wt[I_N][H_N];   // wt[k][j] = Wih[j][k], 64 KB
    const int tid = threadIdx.x;

    {
        const float4* w4 = (const float4*)Wih;
        #pragma unroll
        for (int it = 0; it < 16; ++it) {
            int i = tid * 16 + it;          // 0..4095 float4s
            float4 v = w4[i];
            int r = i >> 5;                 // W row j
            int k = (i & 31) << 2;          // k base
            wt[k + 0][r] = v.x;
            wt[k + 1][r] = v.y;
            wt[k + 2][r] = v.z;
            wt[k + 3][r] = v.w;
        }
    }
    __syncthreads();

    const int  tx   = tid & 15;
    const int  ty   = tid >> 4;
    const long row0 = (long)blockIdx.x * 128;
    const float* xbase = x + (row0 + ty * 8) * I_N;

    float acc[8][8];
    #pragma unroll
    for (int r = 0; r < 8; ++r)
        #pragma unroll
        for (int c = 0; c < 8; ++c) acc[r][c] = 0.0f;

    #pragma unroll 2
    for (int k4 = 0; k4 < I_N / 4; ++k4) {
        float4 xv[8];
        #pragma unroll
        for (int r = 0; r < 8; ++r)
            xv[r] = *(const float4*)(xbase + r * I_N + k4 * 4);

        #pragma unroll
        for (int kk = 0; kk < 4; ++kk) {
            int k = k4 * 4 + kk;
            float4 w0 = *(const float4*)&wt[k][tx * 4];
            float4 w1 = *(const float4*)&wt[k][64 + tx * 4];
            #pragma unroll
            for (int r = 0; r < 8; ++r) {
                float xk = (kk == 0) ? xv[r].x : (kk == 1) ? xv[r].y
                         : (kk == 2) ? xv[r].z : xv[r].w;
                acc[r][0] = fmaf(xk, w0.x, acc[r][0]);
                acc[r][1] = fmaf(xk, w0.y, acc[r][1]);
                acc[r][2] = fmaf(xk, w0.z, acc[r][2]);
                acc[r][3] = fmaf(xk, w0.w, acc[r][3]);
                acc[r][4] = fmaf(xk, w1.x, acc[r][4]);
                acc[r][5] = fmaf(xk, w1.y, acc[r][5]);
                acc[r][6] = fmaf(xk, w1.z, acc[r][6]);
                acc[r][7] = fmaf(xk, w1.w, acc[r][7]);
            }
        }
    }

    float4 b0 = *(const float4*)(bih + tx * 4);
    float4 b1 = *(const float4*)(bih + 64 + tx * 4);
    #pragma unroll
    for (int r = 0; r < 8; ++r) {
        long row = row0 + ty * 8 + r;
        float4 o0, o1;
        o0.x = acc[r][0] + b0.x;  o0.y = acc[r][1] + b0.y;
        o0.z = acc[r][2] + b0.z;  o0.w = acc[r][3] + b0.w;
        o1.x = acc[r][4] + b1.x;  o1.y = acc[r][5] + b1.y;
        o1.z = acc[r][6] + b1.z;  o1.w = acc[r][7] + b1.w;
        *(float4*)(xp + row * H_N + tx * 4)      = o0;
        *(float4*)(xp + row * H_N + 64 + tx * 4) = o1;
    }
}

// ---------------------------------------------------------------------------
// Phase 2: scan — EXACT revert to the R9 kernel (best measured: 1398 us).
// 64 blocks x 512 threads (8 waves = 2/SIMD, the measured occupancy
// optimum). Thread (p = lane&3 -> k-chunk [32p,32p+32), j = (lane>>2) +
// 16*wave). Per step/thread: 8 ds_read_b128 (conflict-free hbuf[2][4][36],
// 4-distinct-address broadcasts), 8 parallel DOT4 + 3-level tree, 2 DPP
// quad-perm reduce rounds, tanh/ds_write/out-store exec-masked to p==0.
// Machinery: ds_write -> s_waitcnt lgkmcnt(0) -> s_barrier -> ds_read;
// global h-store post-barrier; xp prefetched 4 steps ahead.
// Measured step budget (R7/R8 probes): barrier 165 + LDS handoff 170 +
// VALU ~240/SIMD + global ~105 ~= 760 cyc/step @ 2.23 GHz.
// ---------------------------------------------------------------------------
__device__ __forceinline__ float tanh_pade(float x) {
    float u = x * x;
    float n = fmaf(u, u + 105.0f, 945.0f);              // u^2 + 105u + 945
    float d = fmaf(u, fmaf(15.0f, u, 420.0f), 945.0f);  // 15u^2 + 420u + 945
    float t = x * n * __builtin_amdgcn_rcpf(d);
    return fminf(1.0f, fmaxf(-1.0f, t));                // v_med3_f32
}

#define DPP_XOR1 0xB1   // quad_perm [1,0,3,2]
#define DPP_XOR2 0x4E   // quad_perm [2,3,0,1]

__device__ __forceinline__ float dpp_add(float v, const int ctrl) {
    int s = __float_as_int(v);
    int r;
    switch (ctrl) {  // ctrl must be a literal
        case DPP_XOR1: r = __builtin_amdgcn_update_dpp(0, s, DPP_XOR1, 0xF, 0xF, true); break;
        default:       r = __builtin_amdgcn_update_dpp(0, s, DPP_XOR2, 0xF, 0xF, true); break;
    }
    return v + __int_as_float(r);
}

#define DOT4(W4, H4)                                                          \
    fmaf((W4).x, (H4).x, fmaf((W4).y, (H4).y,                                 \
    fmaf((W4).z, (H4).z, (W4).w * (H4).w)))

__global__ __launch_bounds__(512, 1) void scan_kernel(
    const float* __restrict__ Whh, const float* __restrict__ bhh,
    const float* __restrict__ h0, float* __restrict__ out)
{
    const int tid  = threadIdx.x;
    const int b    = blockIdx.x;
    const int lane = tid & 63;
    const int wv   = tid >> 6;                 // 0..7
    const int p    = lane & 3;                 // k-chunk [32p, 32p+32)
    const int j    = (lane >> 2) + 16 * wv;    // output row 0..127
    __shared__ float hbuf[2][4][36];           // [buf][k-chunk][32 + 4 pad]

    // W fragment: w[c] = Whh[j][32p + 4c .. +4), 32 floats
    float4 w[8];
    #pragma unroll
    for (int c = 0; c < 8; ++c)
        w[c] = *(const float4*)(Whh + j * H_N + 32 * p + 4 * c);

    const float bh = bhh[j];

    if (tid < H_N) hbuf[0][tid >> 5][tid & 31] = h0[b * H_N + tid];

    const float* xq = out + b * H_N + j;   // xp (t,b,j) at xq + t*BH
    float*       oq = out + b * H_N + j;

    float xv[4];
    #pragma unroll
    for (int d = 0; d < 4; ++d)
        xv[d] = xq[(size_t)d * BH];

    __syncthreads();

#define RNN_STEP(T0, D, CUR) do {                                             \
        const float4* hb = (const float4*)&hbuf[CUR][p][0];                   \
        float4 hv0 = hb[0], hv1 = hb[1], hv2 = hb[2], hv3 = hb[3];            \
        float4 hv4 = hb[4], hv5 = hb[5], hv6 = hb[6], hv7 = hb[7];            \
        float d01 = DOT4(w[0], hv0) + DOT4(w[1], hv1);                        \
        float d23 = DOT4(w[2], hv2) + DOT4(w[3], hv3);                        \
        float d45 = DOT4(w[4], hv4) + DOT4(w[5], hv5);                        \
        float d67 = DOT4(w[6], hv6) + DOT4(w[7], hv7);                        \
        float s = (d01 + d23) + (d45 + d67);                                  \
        s = dpp_add(s, DPP_XOR1);                                             \
        s = dpp_add(s, DPP_XOR2);                                             \
        float hj;                                                             \
        if (p == 0) {                                                         \
            hj = tanh_pade(s + xv[D] + bh);                                   \
            hbuf[(CUR) ^ 1][j >> 5][j & 31] = hj;                             \
        }                                                                     \
        if ((T0) + 4 < T_N)                                                   \
            xv[D] = xq[(size_t)((T0) + 4) * BH];                              \
        asm volatile("s_waitcnt lgkmcnt(0)" ::: "memory");                    \
        __builtin_amdgcn_s_barrier();                                         \
        if (p == 0) {                                                         \
            oq[(size_t)(T0) * BH] = hj;                                       \
            if ((T0) == T_N - 1) oq[(size_t)T_N * BH] = hj;                   \
        }                                                                     \
        asm volatile("" ::: "memory");                                        \
    } while (0)

    for (int t = 0; t < T_N; t += 4) {
        RNN_STEP(t + 0, 0, 0);
        RNN_STEP(t + 1, 1, 1);
        RNN_STEP(t + 2, 2, 0);
        RNN_STEP(t + 3, 3, 1);
    }
#undef RNN_STEP
}

extern "C" void kernel_launch(void* const* d_in, const int* in_sizes, int n_in,
                              void* d_out, int out_size, void* d_ws, size_t ws_size,
                              hipStream_t stream) {
    const float* x   = (const float*)d_in[0];
    const float* h0  = (const float*)d_in[1];
    const float* Wih = (const float*)d_in[2];
    const float* Whh = (const float*)d_in[3];
    const float* bih = (const float*)d_in[4];
    const float* bhh = (const float*)d_in[5];
    float* out = (float*)d_out;

    xproj_kernel<<<dim3((T_N * B_N) / 128), 256, 0, stream>>>(x, Wih, bih, out);
    scan_kernel<<<dim3(B_N), 512, 0, stream>>>(Whh, bhh, h0, out);
}